// Round 1
// baseline (248.765 us; speedup 1.0000x reference)
//
#include <hip/hip_runtime.h>
#include <hip/hip_bf16.h>
#include <math.h>

// N = 100000, E = 3.2M, F_in = 128, H = C = 16. int inputs arrive as int32.
//
// out[d] = dinv[d]*(sum_{s->d} u[s] + u[d]) + b,  u = dinv .* (h @ W).
// R3: global f32 atomics ~19.5G txn/s. R5: LDS f32 atomics ~3cy/lane.
// R6: sort->CSR->register gather. R7: bf16 messages. R8: 2-pass radix bin.
// R9: XCD swizzle. R10: pipelined gathers = 242us. R11/R12 binning
// restructures both REGRESSED -> reverted to R10.
// R13: R10 + uint2 gather lanes (4 ch/lane, 16 slots) = 234us (BEST).
// R14: kill the per-iteration dependent-load chain in the gather loop:
//      (a) rowptr for the wave's 16 nodes preloaded once (coalesced, lane<16)
//          and re-broadcast per-iteration via __shfl (was: fresh L2 load ->
//          immediate use -> ~200cy stall every iteration);
//      (b) sorted[] prefetched at distance 2, uv gathers at distance 1, all
//          issued at the TOP of each iteration; buffers statically [t&1]
//          under full unroll so nothing goes to scratch.

#define F_IN 128
#define H 16
#define NPB 128            // nodes per bucket
#define MAX_NB 800         // max buckets (N <= 102400)
#define NBLK 256           // binning blocks (must match hist partition)
#define BINT 1024          // binning threads per block
#define SMAX 4864          // max edges per bucket (mean 4096, +12 sigma)
#define PFD 3              // prefetch depth: 16 slots * 3 = 48 edges covered

typedef __hip_bfloat16 bf16;

__device__ __forceinline__ float bflo(unsigned v) { return __uint_as_float(v << 16); }
__device__ __forceinline__ float bfhi(unsigned v) { return __uint_as_float(v & 0xffff0000u); }

// physical block -> logical block so logically-adjacent blocks (adjacent output
// runs in packed[]) land on the same XCD (XCD = physical % 8 round-robin).
__device__ __forceinline__ int swz(int p) { return (p & 7) * 32 + (p >> 3); }

// ---- pass A: per-block bucket histogram -> hist_t[bucket*NBLK + block] ----
__global__ void histA_kernel(const int* __restrict__ dst, int* __restrict__ hist_t,
                             int E, int NB) {
    __shared__ int h[MAX_NB];
    int b = swz(blockIdx.x);
    long long e0 = (long long)E * b / NBLK;
    long long e1 = (long long)E * (b + 1) / NBLK;
    for (int i = threadIdx.x; i < NB; i += BINT) h[i] = 0;
    __syncthreads();
    for (long long e = e0 + threadIdx.x; e < e1; e += BINT)
        atomicAdd(&h[dst[e] >> 7], 1);
    __syncthreads();
    for (int i = threadIdx.x; i < NB; i += BINT) hist_t[i * NBLK + b] = h[i];
}

// ---- pass B1: per-bucket exclusive scan over blocks + bucket totals ----
__global__ void colscan_kernel(int* __restrict__ hist_t, int* __restrict__ btot) {
    __shared__ int s[NBLK];
    int j = blockIdx.x;
    int t = threadIdx.x;
    int v = hist_t[j * NBLK + t];
    s[t] = v;
    __syncthreads();
    for (int off = 1; off < NBLK; off <<= 1) {
        int w = (t >= off) ? s[t - off] : 0;
        __syncthreads();
        s[t] += w;
        __syncthreads();
    }
    hist_t[j * NBLK + t] = s[t] - v;
    if (t == NBLK - 1) btot[j] = s[t];
}

// ---- pass B2: exclusive scan over bucket totals -> base[] ----
__global__ void bucketscan_kernel(const int* __restrict__ btot, int* __restrict__ base, int NB) {
    __shared__ int s[1024];
    int t = threadIdx.x;
    s[t] = (t < NB) ? btot[t] : 0;
    __syncthreads();
    for (int off = 1; off < 1024; off <<= 1) {
        int v = (t >= off) ? s[t - off] : 0;
        __syncthreads();
        s[t] += v;
        __syncthreads();
    }
    if (t < NB) base[t] = s[t] - btot[t];
    if (t == NB - 1) base[NB] = s[t];
}

// ---- pass C: place edges; packed = (dst&127)<<17 | src; LDS cursors only ----
__global__ void binC_kernel(const int* __restrict__ src, const int* __restrict__ dst,
                            const int* __restrict__ hist_t, const int* __restrict__ base,
                            unsigned* __restrict__ packed, int E, int NB) {
    __shared__ int pos[MAX_NB];
    int b = swz(blockIdx.x);
    long long e0 = (long long)E * b / NBLK;
    long long e1 = (long long)E * (b + 1) / NBLK;
    for (int i = threadIdx.x; i < NB; i += BINT)
        pos[i] = base[i] + hist_t[i * NBLK + b];
    __syncthreads();
    for (long long e = e0 + threadIdx.x; e < e1; e += BINT) {
        int d = dst[e];
        int bk = d >> 7;
        int p = atomicAdd(&pos[bk], 1);
        packed[p] = (unsigned)src[e] | ((unsigned)(d & 127) << 17);
    }
}

// ---- pass D: per-bucket LDS counting sort -> sorted[], rowptr[], dinv[] ----
__global__ void sortcsr_kernel(const unsigned* __restrict__ packed, const int* __restrict__ base,
                               unsigned* __restrict__ sorted, int* __restrict__ rowptr,
                               float* __restrict__ dinv, int N, int E) {
    __shared__ unsigned ssort[SMAX];
    __shared__ int cnt[NPB], offs[NPB], cur[NPB];
    int b = blockIdx.x;
    int e0 = base[b];
    int len = base[b + 1] - e0;
    if (len > SMAX) len = SMAX;
    int T = blockDim.x;

    for (int i = threadIdx.x; i < NPB; i += T) cnt[i] = 0;
    __syncthreads();
    for (int i = threadIdx.x; i < len; i += T)
        atomicAdd(&cnt[packed[e0 + i] >> 17], 1);
    __syncthreads();
    if (threadIdx.x < NPB) offs[threadIdx.x] = cnt[threadIdx.x];
    __syncthreads();
    for (int off = 1; off < NPB; off <<= 1) {
        int v = 0;
        if (threadIdx.x < NPB && threadIdx.x >= off) v = offs[threadIdx.x - off];
        __syncthreads();
        if (threadIdx.x < NPB) offs[threadIdx.x] += v;
        __syncthreads();
    }
    if (threadIdx.x < NPB) {
        int ex = offs[threadIdx.x] - cnt[threadIdx.x];
        cur[threadIdx.x] = ex;
        int node = b * NPB + threadIdx.x;
        if (node < N) {
            rowptr[node] = e0 + ex;
            dinv[node] = rsqrtf(1.0f + (float)cnt[threadIdx.x]);
        }
    }
    __syncthreads();
    for (int i = threadIdx.x; i < len; i += T) {
        unsigned p = packed[e0 + i];
        int pos = atomicAdd(&cur[p >> 17], 1);
        ssort[pos] = p;
    }
    __syncthreads();
    for (int i = threadIdx.x; i < len; i += T) sorted[e0 + i] = ssort[i];
    if (b == 0 && threadIdx.x == 0) rowptr[N] = E;
}

// ---- u[i][j] = dinv[i] * sum_k x[i][k]*W1[k][j]  (bf16 out) ----
#define XPAD 132
__global__ void xw1_kernel(const float* __restrict__ x, const float* __restrict__ W1,
                           const float* __restrict__ dinv, bf16* __restrict__ u, int n) {
    __shared__ float sW1[F_IN * H];
    __shared__ float sx[16 * XPAD];
    for (int t = threadIdx.x; t < F_IN * H; t += blockDim.x) sW1[t] = W1[t];

    int basei = blockIdx.x * 16;
    for (int idx = threadIdx.x; idx < 512; idx += 256) {
        int r = idx >> 5;
        int kk = (idx & 31) << 2;
        int row = basei + r;
        float4 v = make_float4(0.f, 0.f, 0.f, 0.f);
        if (row < n) v = *(const float4*)(x + (size_t)row * F_IN + kk);
        *(float4*)(sx + r * XPAD + kk) = v;
    }
    __syncthreads();

    int r = threadIdx.x >> 4;
    int j = threadIdx.x & 15;
    int row = basei + r;
    if (row >= n) return;

    const float* xr = sx + r * XPAD;
    float acc = 0.0f;
#pragma unroll 16
    for (int k = 0; k < F_IN; k++) acc += xr[k] * sW1[k * H + j];
    u[(size_t)row * H + j] = __float2bfloat16(dinv[row] * acc);
}

// ================= pipelined gather core (shared by both layers) =============
// lane = (channel-quad j4 0..3) x (slot g 0..15). Each lane loads uint2 =
// 4 bf16 channels. R14 pipeline over the 16 nodes a wave owns:
//   - rowptr preloaded once per wave (lane<16, coalesced), __shfl per iter;
//   - sorted[] at distance 2, uv gathers at distance 1, issued at top of iter;
//   - static [t&1] double-buffers under full unroll (no scratch).
#define GATHER_TILE(UVPTR)                                                      \
    int lane = threadIdx.x & 63;                                                \
    int wave = threadIdx.x >> 6;                                                \
    int j4 = lane & 3, g = lane >> 2;                                           \
    int nodeBase = blockIdx.x * 64 + wave * 16;                                 \
    int rA = 0, rB = 0;                                                         \
    {   int nl = nodeBase + lane;                                               \
        if (lane < 16 && nl < N) { rA = rowptr[nl]; rB = rowptr[nl + 1]; }      \
    }                                                                           \
    unsigned sv[2][PFD]; uint2 uv[2][PFD];                                      \
    {   /* prologue: sorted for t=0,1; uv for t=0 */                            \
        int p00 = __shfl(rA, 0), p01 = __shfl(rB, 0);                           \
        int p10 = __shfl(rA, 1), p11 = __shfl(rB, 1);                           \
        _Pragma("unroll")                                                       \
        for (int m = 0; m < PFD; m++) {                                         \
            int k = p00 + g + 16 * m;                                           \
            if (k < p01) sv[0][m] = sorted[k];                                  \
        }                                                                       \
        _Pragma("unroll")                                                       \
        for (int m = 0; m < PFD; m++) {                                         \
            int k = p10 + g + 16 * m;                                           \
            if (k < p11) sv[1][m] = sorted[k];                                  \
        }                                                                       \
        _Pragma("unroll")                                                       \
        for (int m = 0; m < PFD; m++) {                                         \
            int k = p00 + g + 16 * m;                                           \
            if (k < p01) uv[0][m] = UVPTR[(size_t)(sv[0][m] & 0x1FFFF) * 4 + j4]; \
        }                                                                       \
    }                                                                           \
    _Pragma("unroll")                                                           \
    for (int t = 0; t < 16; t++) {                                              \
        if (t + 2 < 16) {       /* issue sorted for node t+2 into sv[t&1] */    \
            int rn0 = __shfl(rA, t + 2), rn1 = __shfl(rB, t + 2);               \
            _Pragma("unroll")                                                   \
            for (int m = 0; m < PFD; m++) {                                     \
                int k = rn0 + g + 16 * m;                                       \
                if (k < rn1) sv[t & 1][m] = sorted[k];                          \
            }                                                                   \
        }                                                                       \
        if (t + 1 < 16) {       /* issue gathers for node t+1 from sv[~t&1] */  \
            int rn0 = __shfl(rA, t + 1), rn1 = __shfl(rB, t + 1);               \
            _Pragma("unroll")                                                   \
            for (int m = 0; m < PFD; m++) {                                     \
                int k = rn0 + g + 16 * m;                                       \
                if (k < rn1) uv[(t + 1) & 1][m] =                               \
                    UVPTR[(size_t)(sv[(t + 1) & 1][m] & 0x1FFFF) * 4 + j4];     \
            }                                                                   \
        }                                                                       \
        int rc0 = __shfl(rA, t), rc1 = __shfl(rB, t);                           \
        float ax = 0.f, ay = 0.f, az = 0.f, aw = 0.f;                           \
        _Pragma("unroll")                                                       \
        for (int m = 0; m < PFD; m++) {                                         \
            int k = rc0 + g + 16 * m;                                           \
            if (k < rc1) {                                                      \
                ax += bflo(uv[t & 1][m].x); ay += bfhi(uv[t & 1][m].x);         \
                az += bflo(uv[t & 1][m].y); aw += bfhi(uv[t & 1][m].y);         \
            }                                                                   \
        }                                                                       \
        for (int k = rc0 + g + 16 * PFD; k < rc1; k += 16) {                    \
            uint2 va = UVPTR[(size_t)(sorted[k] & 0x1FFFF) * 4 + j4];           \
            ax += bflo(va.x); ay += bfhi(va.x);                                 \
            az += bflo(va.y); aw += bfhi(va.y);                                 \
        }                                                                       \
        ax += __shfl_xor(ax, 4);  ay += __shfl_xor(ay, 4);                      \
        az += __shfl_xor(az, 4);  aw += __shfl_xor(aw, 4);                      \
        ax += __shfl_xor(ax, 8);  ay += __shfl_xor(ay, 8);                      \
        az += __shfl_xor(az, 8);  aw += __shfl_xor(aw, 8);                      \
        ax += __shfl_xor(ax, 16); ay += __shfl_xor(ay, 16);                     \
        az += __shfl_xor(az, 16); aw += __shfl_xor(aw, 16);                     \
        ax += __shfl_xor(ax, 32); ay += __shfl_xor(ay, 32);                     \
        az += __shfl_xor(az, 32); aw += __shfl_xor(aw, 32);                     \
        if (g == 0) {                                                           \
            float* tp = &tile[(wave * 16 + t) * 16 + 4 * j4];                   \
            tp[0] = ax; tp[1] = ay; tp[2] = az; tp[3] = aw;                     \
        }                                                                       \
    }

// ---- layer-1 gather + finalize ----
__global__ void gatherfin1_kernel(const unsigned* __restrict__ sorted, const int* __restrict__ rowptr,
                                  const bf16* __restrict__ u, const float* __restrict__ dinv,
                                  const float* __restrict__ b1, const float* __restrict__ W2,
                                  bf16* __restrict__ u2, int N) {
    __shared__ float tile[64 * 16];
    __shared__ float sW2[256];
    __shared__ float sb1[16];
    sW2[threadIdx.x] = W2[threadIdx.x];
    if (threadIdx.x < 16) sb1[threadIdx.x] = b1[threadIdx.x];

    const uint2* uvp = (const uint2*)u;   // [node*4 + j4] channel quads
    GATHER_TILE(uvp)
    __syncthreads();

    int jj = threadIdx.x & 15;
    for (int rr = 0; rr < 4; rr++) {
        int rl = (threadIdx.x >> 4) + rr * 16;
        int node = blockIdx.x * 64 + rl;
        float h = 0.f, di = 0.f;
        if (node < N) {
            di = dinv[node];
            h = di * (tile[rl * 16 + jj] + __bfloat162float(u[(size_t)node * H + jj])) + sb1[jj];
            h = fmaxf(h, 0.f);
        }
        float acc2 = 0.f;
#pragma unroll
        for (int kk = 0; kk < 16; kk++) {
            float hk = __shfl(h, kk, 16);
            acc2 += hk * sW2[kk * 16 + jj];
        }
        if (node < N) u2[(size_t)node * H + jj] = __float2bfloat16(di * acc2);
    }
}

// ---- layer-2 gather + finalize: log_softmax -> out (f32) ----
__global__ void gatherfin2_kernel(const unsigned* __restrict__ sorted, const int* __restrict__ rowptr,
                                  const bf16* __restrict__ u2, const float* __restrict__ dinv,
                                  const float* __restrict__ b2, float* __restrict__ out, int N) {
    __shared__ float tile[64 * 16];
    __shared__ float sb2[16];
    if (threadIdx.x < 16) sb2[threadIdx.x] = b2[threadIdx.x];

    const uint2* uvp = (const uint2*)u2;
    GATHER_TILE(uvp)
    __syncthreads();

    int jj = threadIdx.x & 15;
    for (int rr = 0; rr < 4; rr++) {
        int rl = (threadIdx.x >> 4) + rr * 16;
        int node = blockIdx.x * 64 + rl;
        if (node >= N) continue;
        float di = dinv[node];
        float v = di * (tile[rl * 16 + jj] + __bfloat162float(u2[(size_t)node * H + jj])) + sb2[jj];

        float m = v;
#pragma unroll
        for (int off = 8; off >= 1; off >>= 1) m = fmaxf(m, __shfl_xor(m, off, 16));
        float ex = __expf(v - m);
        float s = ex;
#pragma unroll
        for (int off = 8; off >= 1; off >>= 1) s += __shfl_xor(s, off, 16);

        out[(size_t)node * H + jj] = v - m - __logf(s);
    }
}

extern "C" void kernel_launch(void* const* d_in, const int* in_sizes, int n_in,
                              void* d_out, int out_size, void* d_ws, size_t ws_size,
                              hipStream_t stream) {
    const float* x = (const float*)d_in[0];
    const int* edge_index = (const int*)d_in[1];
    const float* W1 = (const float*)d_in[2];
    const float* b1 = (const float*)d_in[3];
    const float* W2 = (const float*)d_in[4];
    const float* b2 = (const float*)d_in[5];
    float* out = (float*)d_out;

    const int N = in_sizes[0] / F_IN;        // 100000
    const int E = in_sizes[1] / 2;           // 3200000
    const int* src = edge_index;
    const int* dst = edge_index + E;
    const int NB = (N + NPB - 1) / NPB;      // 782

    // ws (4B units): dinv[N] | u[8N] | u2[8N] | packed[E] | sorted[E] |
    //                hist_t[MAX_NB*NBLK] | rowptr[N+1] | btot[NB] | base[NB+1]
    float* dinv = (float*)d_ws;
    bf16* u = (bf16*)(dinv + N);
    bf16* u2 = (bf16*)((unsigned*)u + (size_t)N * H / 2);
    unsigned* packed = (unsigned*)((unsigned*)u2 + (size_t)N * H / 2);
    unsigned* sorted = packed + E;
    int* hist_t = (int*)(sorted + E);
    int* rowptr = hist_t + (size_t)MAX_NB * NBLK;
    int* btot = rowptr + N + 1;
    int* base = btot + NB;

    histA_kernel<<<NBLK, BINT, 0, stream>>>(dst, hist_t, E, NB);
    colscan_kernel<<<NB, NBLK, 0, stream>>>(hist_t, btot);
    bucketscan_kernel<<<1, 1024, 0, stream>>>(btot, base, NB);
    binC_kernel<<<NBLK, BINT, 0, stream>>>(src, dst, hist_t, base, packed, E, NB);
    sortcsr_kernel<<<NB, 512, 0, stream>>>(packed, base, sorted, rowptr, dinv, N, E);

    xw1_kernel<<<(N + 15) / 16, 256, 0, stream>>>(x, W1, dinv, u, N);
    gatherfin1_kernel<<<(N + 63) / 64, 256, 0, stream>>>(sorted, rowptr, u, dinv, b1, W2, u2, N);
    gatherfin2_kernel<<<(N + 63) / 64, 256, 0, stream>>>(sorted, rowptr, u2, dinv, b2, out, N);
}

// Round 2
// 239.671 us; speedup vs baseline: 1.0379x; 1.0379x over previous
//
#include <hip/hip_runtime.h>
#include <hip/hip_bf16.h>
#include <math.h>

// N = 100000, E = 3.2M, F_in = 128, H = C = 16. int inputs arrive as int32.
//
// out[d] = dinv[d]*(sum_{s->d} u[s] + u[d]) + b,  u = dinv .* (h @ W).
// R3: global f32 atomics ~19.5G txn/s. R5: LDS f32 atomics ~3cy/lane.
// R6: sort->CSR->register gather. R7: bf16 messages. R8: 2-pass radix bin.
// R9: XCD swizzle. R10: pipelined gathers = 242us. R11/R12 binning
// restructures both REGRESSED -> reverted to R10.
// R13: R10 + uint2 gather lanes (4 ch/lane, 16 slots) = 234us (BEST).
// R14 REGRESSED (248.8us; gatherfin1 47.3us, VALUBusy 22.6%, Occ 44%):
//      deeper pipeline + __shfl rowptr broadcast, but conditional prefetch
//      loads forced exec-mask branches + conservative vmcnt drains.
// R15: revert to R13 pipeline shape; make ALL prefetch loads unconditional
//      with clamped index min(k, E-1) (always in-bounds, stale data masked
//      out at accumulate time in registers). No branches around VMEM issue.

#define F_IN 128
#define H 16
#define NPB 128            // nodes per bucket
#define MAX_NB 800         // max buckets (N <= 102400)
#define NBLK 256           // binning blocks (must match hist partition)
#define BINT 1024          // binning threads per block
#define SMAX 4864          // max edges per bucket (mean 4096, +12 sigma)
#define PFD 3              // prefetch depth: 16 slots * 3 = 48 edges covered

typedef __hip_bfloat16 bf16;

__device__ __forceinline__ float bflo(unsigned v) { return __uint_as_float(v << 16); }
__device__ __forceinline__ float bfhi(unsigned v) { return __uint_as_float(v & 0xffff0000u); }

// physical block -> logical block so logically-adjacent blocks (adjacent output
// runs in packed[]) land on the same XCD (XCD = physical % 8 round-robin).
__device__ __forceinline__ int swz(int p) { return (p & 7) * 32 + (p >> 3); }

// ---- pass A: per-block bucket histogram -> hist_t[bucket*NBLK + block] ----
__global__ void histA_kernel(const int* __restrict__ dst, int* __restrict__ hist_t,
                             int E, int NB) {
    __shared__ int h[MAX_NB];
    int b = swz(blockIdx.x);
    long long e0 = (long long)E * b / NBLK;
    long long e1 = (long long)E * (b + 1) / NBLK;
    for (int i = threadIdx.x; i < NB; i += BINT) h[i] = 0;
    __syncthreads();
    for (long long e = e0 + threadIdx.x; e < e1; e += BINT)
        atomicAdd(&h[dst[e] >> 7], 1);
    __syncthreads();
    for (int i = threadIdx.x; i < NB; i += BINT) hist_t[i * NBLK + b] = h[i];
}

// ---- pass B1: per-bucket exclusive scan over blocks + bucket totals ----
__global__ void colscan_kernel(int* __restrict__ hist_t, int* __restrict__ btot) {
    __shared__ int s[NBLK];
    int j = blockIdx.x;
    int t = threadIdx.x;
    int v = hist_t[j * NBLK + t];
    s[t] = v;
    __syncthreads();
    for (int off = 1; off < NBLK; off <<= 1) {
        int w = (t >= off) ? s[t - off] : 0;
        __syncthreads();
        s[t] += w;
        __syncthreads();
    }
    hist_t[j * NBLK + t] = s[t] - v;
    if (t == NBLK - 1) btot[j] = s[t];
}

// ---- pass B2: exclusive scan over bucket totals -> base[] ----
__global__ void bucketscan_kernel(const int* __restrict__ btot, int* __restrict__ base, int NB) {
    __shared__ int s[1024];
    int t = threadIdx.x;
    s[t] = (t < NB) ? btot[t] : 0;
    __syncthreads();
    for (int off = 1; off < 1024; off <<= 1) {
        int v = (t >= off) ? s[t - off] : 0;
        __syncthreads();
        s[t] += v;
        __syncthreads();
    }
    if (t < NB) base[t] = s[t] - btot[t];
    if (t == NB - 1) base[NB] = s[t];
}

// ---- pass C: place edges; packed = (dst&127)<<17 | src; LDS cursors only ----
__global__ void binC_kernel(const int* __restrict__ src, const int* __restrict__ dst,
                            const int* __restrict__ hist_t, const int* __restrict__ base,
                            unsigned* __restrict__ packed, int E, int NB) {
    __shared__ int pos[MAX_NB];
    int b = swz(blockIdx.x);
    long long e0 = (long long)E * b / NBLK;
    long long e1 = (long long)E * (b + 1) / NBLK;
    for (int i = threadIdx.x; i < NB; i += BINT)
        pos[i] = base[i] + hist_t[i * NBLK + b];
    __syncthreads();
    for (long long e = e0 + threadIdx.x; e < e1; e += BINT) {
        int d = dst[e];
        int bk = d >> 7;
        int p = atomicAdd(&pos[bk], 1);
        packed[p] = (unsigned)src[e] | ((unsigned)(d & 127) << 17);
    }
}

// ---- pass D: per-bucket LDS counting sort -> sorted[], rowptr[], dinv[] ----
__global__ void sortcsr_kernel(const unsigned* __restrict__ packed, const int* __restrict__ base,
                               unsigned* __restrict__ sorted, int* __restrict__ rowptr,
                               float* __restrict__ dinv, int N, int E) {
    __shared__ unsigned ssort[SMAX];
    __shared__ int cnt[NPB], offs[NPB], cur[NPB];
    int b = blockIdx.x;
    int e0 = base[b];
    int len = base[b + 1] - e0;
    if (len > SMAX) len = SMAX;
    int T = blockDim.x;

    for (int i = threadIdx.x; i < NPB; i += T) cnt[i] = 0;
    __syncthreads();
    for (int i = threadIdx.x; i < len; i += T)
        atomicAdd(&cnt[packed[e0 + i] >> 17], 1);
    __syncthreads();
    if (threadIdx.x < NPB) offs[threadIdx.x] = cnt[threadIdx.x];
    __syncthreads();
    for (int off = 1; off < NPB; off <<= 1) {
        int v = 0;
        if (threadIdx.x < NPB && threadIdx.x >= off) v = offs[threadIdx.x - off];
        __syncthreads();
        if (threadIdx.x < NPB) offs[threadIdx.x] += v;
        __syncthreads();
    }
    if (threadIdx.x < NPB) {
        int ex = offs[threadIdx.x] - cnt[threadIdx.x];
        cur[threadIdx.x] = ex;
        int node = b * NPB + threadIdx.x;
        if (node < N) {
            rowptr[node] = e0 + ex;
            dinv[node] = rsqrtf(1.0f + (float)cnt[threadIdx.x]);
        }
    }
    __syncthreads();
    for (int i = threadIdx.x; i < len; i += T) {
        unsigned p = packed[e0 + i];
        int pos = atomicAdd(&cur[p >> 17], 1);
        ssort[pos] = p;
    }
    __syncthreads();
    for (int i = threadIdx.x; i < len; i += T) sorted[e0 + i] = ssort[i];
    if (b == 0 && threadIdx.x == 0) rowptr[N] = E;
}

// ---- u[i][j] = dinv[i] * sum_k x[i][k]*W1[k][j]  (bf16 out) ----
#define XPAD 132
__global__ void xw1_kernel(const float* __restrict__ x, const float* __restrict__ W1,
                           const float* __restrict__ dinv, bf16* __restrict__ u, int n) {
    __shared__ float sW1[F_IN * H];
    __shared__ float sx[16 * XPAD];
    for (int t = threadIdx.x; t < F_IN * H; t += blockDim.x) sW1[t] = W1[t];

    int basei = blockIdx.x * 16;
    for (int idx = threadIdx.x; idx < 512; idx += 256) {
        int r = idx >> 5;
        int kk = (idx & 31) << 2;
        int row = basei + r;
        float4 v = make_float4(0.f, 0.f, 0.f, 0.f);
        if (row < n) v = *(const float4*)(x + (size_t)row * F_IN + kk);
        *(float4*)(sx + r * XPAD + kk) = v;
    }
    __syncthreads();

    int r = threadIdx.x >> 4;
    int j = threadIdx.x & 15;
    int row = basei + r;
    if (row >= n) return;

    const float* xr = sx + r * XPAD;
    float acc = 0.0f;
#pragma unroll 16
    for (int k = 0; k < F_IN; k++) acc += xr[k] * sW1[k * H + j];
    u[(size_t)row * H + j] = __float2bfloat16(dinv[row] * acc);
}

// ================= pipelined gather core (shared by both layers) =============
// lane = (channel-quad j4 0..3) x (slot g 0..15). Each lane loads uint2 =
// 4 bf16 channels. Depth-2 pipeline over the 16 nodes a wave owns (R13 shape):
// prefetch sorted[t+1] while consuming uv[t] issued last iteration.
// R15: all prefetch loads UNCONDITIONAL with clamped index min(k, Elast) —
// always in-bounds; out-of-row slots load a valid stale edge whose value is
// discarded by the register-side (k < r1) mask at accumulate time.
#define GATHER_TILE(UVPTR, ELAST)                                               \
    int lane = threadIdx.x & 63;                                                \
    int wave = threadIdx.x >> 6;                                                \
    int j4 = lane & 3, g = lane >> 2;                                           \
    int nodeBase = blockIdx.x * 64 + wave * 16;                                 \
    int r0c = 0, r1c = 0;                                                       \
    unsigned svc[PFD]; uint2 uvc[PFD];                                          \
    {   int node = nodeBase;                                                    \
        if (node < N) { r0c = rowptr[node]; r1c = rowptr[node + 1]; }           \
        _Pragma("unroll")                                                       \
        for (int m = 0; m < PFD; m++) {                                         \
            int k = r0c + g + 16 * m;                                           \
            svc[m] = sorted[min(k, ELAST)];                                     \
        }                                                                       \
        _Pragma("unroll")                                                       \
        for (int m = 0; m < PFD; m++)                                           \
            uvc[m] = UVPTR[(size_t)(svc[m] & 0x1FFFF) * 4 + j4];                \
    }                                                                           \
    for (int t = 0; t < 16; t++) {                                              \
        int r0n = 0, r1n = 0;                                                   \
        unsigned svn[PFD];                                                      \
        if (t < 15) {                                                           \
            int nn = nodeBase + t + 1;                                          \
            if (nn < N) { r0n = rowptr[nn]; r1n = rowptr[nn + 1]; }             \
            _Pragma("unroll")                                                   \
            for (int m = 0; m < PFD; m++) {                                     \
                int k = r0n + g + 16 * m;                                       \
                svn[m] = sorted[min(k, ELAST)];                                 \
            }                                                                   \
        }                                                                       \
        float ax = 0.f, ay = 0.f, az = 0.f, aw = 0.f;                           \
        _Pragma("unroll")                                                       \
        for (int m = 0; m < PFD; m++) {                                         \
            int k = r0c + g + 16 * m;                                           \
            if (k < r1c) {                                                      \
                ax += bflo(uvc[m].x); ay += bfhi(uvc[m].x);                     \
                az += bflo(uvc[m].y); aw += bfhi(uvc[m].y);                     \
            }                                                                   \
        }                                                                       \
        for (int k = r0c + g + 16 * PFD; k < r1c; k += 16) {                    \
            uint2 va = UVPTR[(size_t)(sorted[k] & 0x1FFFF) * 4 + j4];           \
            ax += bflo(va.x); ay += bfhi(va.x);                                 \
            az += bflo(va.y); aw += bfhi(va.y);                                 \
        }                                                                       \
        ax += __shfl_xor(ax, 4);  ay += __shfl_xor(ay, 4);                      \
        az += __shfl_xor(az, 4);  aw += __shfl_xor(aw, 4);                      \
        ax += __shfl_xor(ax, 8);  ay += __shfl_xor(ay, 8);                      \
        az += __shfl_xor(az, 8);  aw += __shfl_xor(aw, 8);                      \
        ax += __shfl_xor(ax, 16); ay += __shfl_xor(ay, 16);                     \
        az += __shfl_xor(az, 16); aw += __shfl_xor(aw, 16);                     \
        ax += __shfl_xor(ax, 32); ay += __shfl_xor(ay, 32);                     \
        az += __shfl_xor(az, 32); aw += __shfl_xor(aw, 32);                     \
        if (g == 0) {                                                           \
            float* tp = &tile[(wave * 16 + t) * 16 + 4 * j4];                   \
            tp[0] = ax; tp[1] = ay; tp[2] = az; tp[3] = aw;                     \
        }                                                                       \
        if (t < 15) {                                                           \
            r0c = r0n; r1c = r1n;                                               \
            _Pragma("unroll")                                                   \
            for (int m = 0; m < PFD; m++) {                                     \
                svc[m] = svn[m];                                                \
                uvc[m] = UVPTR[(size_t)(svn[m] & 0x1FFFF) * 4 + j4];            \
            }                                                                   \
        }                                                                       \
    }

// ---- layer-1 gather + finalize ----
__global__ void gatherfin1_kernel(const unsigned* __restrict__ sorted, const int* __restrict__ rowptr,
                                  const bf16* __restrict__ u, const float* __restrict__ dinv,
                                  const float* __restrict__ b1, const float* __restrict__ W2,
                                  bf16* __restrict__ u2, int N, int Elast) {
    __shared__ float tile[64 * 16];
    __shared__ float sW2[256];
    __shared__ float sb1[16];
    sW2[threadIdx.x] = W2[threadIdx.x];
    if (threadIdx.x < 16) sb1[threadIdx.x] = b1[threadIdx.x];

    const uint2* uvp = (const uint2*)u;   // [node*4 + j4] channel quads
    GATHER_TILE(uvp, Elast)
    __syncthreads();

    int jj = threadIdx.x & 15;
    for (int rr = 0; rr < 4; rr++) {
        int rl = (threadIdx.x >> 4) + rr * 16;
        int node = blockIdx.x * 64 + rl;
        float h = 0.f, di = 0.f;
        if (node < N) {
            di = dinv[node];
            h = di * (tile[rl * 16 + jj] + __bfloat162float(u[(size_t)node * H + jj])) + sb1[jj];
            h = fmaxf(h, 0.f);
        }
        float acc2 = 0.f;
#pragma unroll
        for (int kk = 0; kk < 16; kk++) {
            float hk = __shfl(h, kk, 16);
            acc2 += hk * sW2[kk * 16 + jj];
        }
        if (node < N) u2[(size_t)node * H + jj] = __float2bfloat16(di * acc2);
    }
}

// ---- layer-2 gather + finalize: log_softmax -> out (f32) ----
__global__ void gatherfin2_kernel(const unsigned* __restrict__ sorted, const int* __restrict__ rowptr,
                                  const bf16* __restrict__ u2, const float* __restrict__ dinv,
                                  const float* __restrict__ b2, float* __restrict__ out, int N, int Elast) {
    __shared__ float tile[64 * 16];
    __shared__ float sb2[16];
    if (threadIdx.x < 16) sb2[threadIdx.x] = b2[threadIdx.x];

    const uint2* uvp = (const uint2*)u2;
    GATHER_TILE(uvp, Elast)
    __syncthreads();

    int jj = threadIdx.x & 15;
    for (int rr = 0; rr < 4; rr++) {
        int rl = (threadIdx.x >> 4) + rr * 16;
        int node = blockIdx.x * 64 + rl;
        if (node >= N) continue;
        float di = dinv[node];
        float v = di * (tile[rl * 16 + jj] + __bfloat162float(u2[(size_t)node * H + jj])) + sb2[jj];

        float m = v;
#pragma unroll
        for (int off = 8; off >= 1; off >>= 1) m = fmaxf(m, __shfl_xor(m, off, 16));
        float ex = __expf(v - m);
        float s = ex;
#pragma unroll
        for (int off = 8; off >= 1; off >>= 1) s += __shfl_xor(s, off, 16);

        out[(size_t)node * H + jj] = v - m - __logf(s);
    }
}

extern "C" void kernel_launch(void* const* d_in, const int* in_sizes, int n_in,
                              void* d_out, int out_size, void* d_ws, size_t ws_size,
                              hipStream_t stream) {
    const float* x = (const float*)d_in[0];
    const int* edge_index = (const int*)d_in[1];
    const float* W1 = (const float*)d_in[2];
    const float* b1 = (const float*)d_in[3];
    const float* W2 = (const float*)d_in[4];
    const float* b2 = (const float*)d_in[5];
    float* out = (float*)d_out;

    const int N = in_sizes[0] / F_IN;        // 100000
    const int E = in_sizes[1] / 2;           // 3200000
    const int* src = edge_index;
    const int* dst = edge_index + E;
    const int NB = (N + NPB - 1) / NPB;      // 782

    // ws (4B units): dinv[N] | u[8N] | u2[8N] | packed[E] | sorted[E] |
    //                hist_t[MAX_NB*NBLK] | rowptr[N+1] | btot[NB] | base[NB+1]
    float* dinv = (float*)d_ws;
    bf16* u = (bf16*)(dinv + N);
    bf16* u2 = (bf16*)((unsigned*)u + (size_t)N * H / 2);
    unsigned* packed = (unsigned*)((unsigned*)u2 + (size_t)N * H / 2);
    unsigned* sorted = packed + E;
    int* hist_t = (int*)(sorted + E);
    int* rowptr = hist_t + (size_t)MAX_NB * NBLK;
    int* btot = rowptr + N + 1;
    int* base = btot + NB;

    histA_kernel<<<NBLK, BINT, 0, stream>>>(dst, hist_t, E, NB);
    colscan_kernel<<<NB, NBLK, 0, stream>>>(hist_t, btot);
    bucketscan_kernel<<<1, 1024, 0, stream>>>(btot, base, NB);
    binC_kernel<<<NBLK, BINT, 0, stream>>>(src, dst, hist_t, base, packed, E, NB);
    sortcsr_kernel<<<NB, 512, 0, stream>>>(packed, base, sorted, rowptr, dinv, N, E);

    xw1_kernel<<<(N + 15) / 16, 256, 0, stream>>>(x, W1, dinv, u, N);
    gatherfin1_kernel<<<(N + 63) / 64, 256, 0, stream>>>(sorted, rowptr, u, dinv, b1, W2, u2, N, E - 1);
    gatherfin2_kernel<<<(N + 63) / 64, 256, 0, stream>>>(sorted, rowptr, u2, dinv, b2, out, N, E - 1);
}

// Round 3
// 230.937 us; speedup vs baseline: 1.0772x; 1.0378x over previous
//
#include <hip/hip_runtime.h>
#include <hip/hip_bf16.h>
#include <math.h>

// N = 100000, E = 3.2M, F_in = 128, H = C = 16. int inputs arrive as int32.
//
// out[d] = dinv[d]*(sum_{s->d} u[s] + u[d]) + b,  u = dinv .* (h @ W).
// R3: global f32 atomics ~19.5G txn/s. R5: LDS f32 atomics ~3cy/lane.
// R6: sort->CSR->register gather. R7: bf16 messages. R8: 2-pass radix bin.
// R9: XCD swizzle. R10: pipelined gathers = 242us. R11/R12 binning
// restructures both REGRESSED -> reverted to R10.
// R13: R10 + uint2 gather lanes (4 ch/lane, 16 slots) = 234us.
// R14 REGRESSED (248.8us): deeper pipeline + shfl rowptr broadcast.
// R15 NEUTRAL-NEG (239.7us): clamped unconditional prefetch. Counters:
//      gf1 43.6us, VALUBusy 27%, Occ 42%, HBM 7% -> latency-bound with
//      TOO FEW WAVES (grid supplies 24.4/CU vs 32 capacity; imbalance
//      decays the average to ~13/CU).
// R16: exact R13 gather shape; ONLY change = 8 nodes/wave (was 16).
//      Block covers 32 nodes; grid 3125 blocks = 12.5K waves (~49/CU,
//      1.5x oversubscribed) for latency hiding + tail balancing.

#define F_IN 128
#define H 16
#define NPB 128            // nodes per bucket
#define MAX_NB 800         // max buckets (N <= 102400)
#define NBLK 256           // binning blocks (must match hist partition)
#define BINT 1024          // binning threads per block
#define SMAX 4864          // max edges per bucket (mean 4096, +12 sigma)
#define PFD 3              // prefetch depth: 16 slots * 3 = 48 edges covered
#define NPW 8              // nodes per wave (R16: was 16)
#define NPBLK 32           // nodes per block = 4 waves * NPW

typedef __hip_bfloat16 bf16;

__device__ __forceinline__ float bflo(unsigned v) { return __uint_as_float(v << 16); }
__device__ __forceinline__ float bfhi(unsigned v) { return __uint_as_float(v & 0xffff0000u); }

// physical block -> logical block so logically-adjacent blocks (adjacent output
// runs in packed[]) land on the same XCD (XCD = physical % 8 round-robin).
__device__ __forceinline__ int swz(int p) { return (p & 7) * 32 + (p >> 3); }

// ---- pass A: per-block bucket histogram -> hist_t[bucket*NBLK + block] ----
__global__ void histA_kernel(const int* __restrict__ dst, int* __restrict__ hist_t,
                             int E, int NB) {
    __shared__ int h[MAX_NB];
    int b = swz(blockIdx.x);
    long long e0 = (long long)E * b / NBLK;
    long long e1 = (long long)E * (b + 1) / NBLK;
    for (int i = threadIdx.x; i < NB; i += BINT) h[i] = 0;
    __syncthreads();
    for (long long e = e0 + threadIdx.x; e < e1; e += BINT)
        atomicAdd(&h[dst[e] >> 7], 1);
    __syncthreads();
    for (int i = threadIdx.x; i < NB; i += BINT) hist_t[i * NBLK + b] = h[i];
}

// ---- pass B1: per-bucket exclusive scan over blocks + bucket totals ----
__global__ void colscan_kernel(int* __restrict__ hist_t, int* __restrict__ btot) {
    __shared__ int s[NBLK];
    int j = blockIdx.x;
    int t = threadIdx.x;
    int v = hist_t[j * NBLK + t];
    s[t] = v;
    __syncthreads();
    for (int off = 1; off < NBLK; off <<= 1) {
        int w = (t >= off) ? s[t - off] : 0;
        __syncthreads();
        s[t] += w;
        __syncthreads();
    }
    hist_t[j * NBLK + t] = s[t] - v;
    if (t == NBLK - 1) btot[j] = s[t];
}

// ---- pass B2: exclusive scan over bucket totals -> base[] ----
__global__ void bucketscan_kernel(const int* __restrict__ btot, int* __restrict__ base, int NB) {
    __shared__ int s[1024];
    int t = threadIdx.x;
    s[t] = (t < NB) ? btot[t] : 0;
    __syncthreads();
    for (int off = 1; off < 1024; off <<= 1) {
        int v = (t >= off) ? s[t - off] : 0;
        __syncthreads();
        s[t] += v;
        __syncthreads();
    }
    if (t < NB) base[t] = s[t] - btot[t];
    if (t == NB - 1) base[NB] = s[t];
}

// ---- pass C: place edges; packed = (dst&127)<<17 | src; LDS cursors only ----
__global__ void binC_kernel(const int* __restrict__ src, const int* __restrict__ dst,
                            const int* __restrict__ hist_t, const int* __restrict__ base,
                            unsigned* __restrict__ packed, int E, int NB) {
    __shared__ int pos[MAX_NB];
    int b = swz(blockIdx.x);
    long long e0 = (long long)E * b / NBLK;
    long long e1 = (long long)E * (b + 1) / NBLK;
    for (int i = threadIdx.x; i < NB; i += BINT)
        pos[i] = base[i] + hist_t[i * NBLK + b];
    __syncthreads();
    for (long long e = e0 + threadIdx.x; e < e1; e += BINT) {
        int d = dst[e];
        int bk = d >> 7;
        int p = atomicAdd(&pos[bk], 1);
        packed[p] = (unsigned)src[e] | ((unsigned)(d & 127) << 17);
    }
}

// ---- pass D: per-bucket LDS counting sort -> sorted[], rowptr[], dinv[] ----
__global__ void sortcsr_kernel(const unsigned* __restrict__ packed, const int* __restrict__ base,
                               unsigned* __restrict__ sorted, int* __restrict__ rowptr,
                               float* __restrict__ dinv, int N, int E) {
    __shared__ unsigned ssort[SMAX];
    __shared__ int cnt[NPB], offs[NPB], cur[NPB];
    int b = blockIdx.x;
    int e0 = base[b];
    int len = base[b + 1] - e0;
    if (len > SMAX) len = SMAX;
    int T = blockDim.x;

    for (int i = threadIdx.x; i < NPB; i += T) cnt[i] = 0;
    __syncthreads();
    for (int i = threadIdx.x; i < len; i += T)
        atomicAdd(&cnt[packed[e0 + i] >> 17], 1);
    __syncthreads();
    if (threadIdx.x < NPB) offs[threadIdx.x] = cnt[threadIdx.x];
    __syncthreads();
    for (int off = 1; off < NPB; off <<= 1) {
        int v = 0;
        if (threadIdx.x < NPB && threadIdx.x >= off) v = offs[threadIdx.x - off];
        __syncthreads();
        if (threadIdx.x < NPB) offs[threadIdx.x] += v;
        __syncthreads();
    }
    if (threadIdx.x < NPB) {
        int ex = offs[threadIdx.x] - cnt[threadIdx.x];
        cur[threadIdx.x] = ex;
        int node = b * NPB + threadIdx.x;
        if (node < N) {
            rowptr[node] = e0 + ex;
            dinv[node] = rsqrtf(1.0f + (float)cnt[threadIdx.x]);
        }
    }
    __syncthreads();
    for (int i = threadIdx.x; i < len; i += T) {
        unsigned p = packed[e0 + i];
        int pos = atomicAdd(&cur[p >> 17], 1);
        ssort[pos] = p;
    }
    __syncthreads();
    for (int i = threadIdx.x; i < len; i += T) sorted[e0 + i] = ssort[i];
    if (b == 0 && threadIdx.x == 0) rowptr[N] = E;
}

// ---- u[i][j] = dinv[i] * sum_k x[i][k]*W1[k][j]  (bf16 out) ----
#define XPAD 132
__global__ void xw1_kernel(const float* __restrict__ x, const float* __restrict__ W1,
                           const float* __restrict__ dinv, bf16* __restrict__ u, int n) {
    __shared__ float sW1[F_IN * H];
    __shared__ float sx[16 * XPAD];
    for (int t = threadIdx.x; t < F_IN * H; t += blockDim.x) sW1[t] = W1[t];

    int basei = blockIdx.x * 16;
    for (int idx = threadIdx.x; idx < 512; idx += 256) {
        int r = idx >> 5;
        int kk = (idx & 31) << 2;
        int row = basei + r;
        float4 v = make_float4(0.f, 0.f, 0.f, 0.f);
        if (row < n) v = *(const float4*)(x + (size_t)row * F_IN + kk);
        *(float4*)(sx + r * XPAD + kk) = v;
    }
    __syncthreads();

    int r = threadIdx.x >> 4;
    int j = threadIdx.x & 15;
    int row = basei + r;
    if (row >= n) return;

    const float* xr = sx + r * XPAD;
    float acc = 0.0f;
#pragma unroll 16
    for (int k = 0; k < F_IN; k++) acc += xr[k] * sW1[k * H + j];
    u[(size_t)row * H + j] = __float2bfloat16(dinv[row] * acc);
}

// ================= pipelined gather core (shared by both layers) =============
// lane = (channel-quad j4 0..3) x (slot g 0..15). Each lane loads uint2 =
// 4 bf16 channels. Depth-2 pipeline over the NPW nodes a wave owns (R13
// shape): prefetch sorted[t+1] while consuming uv[t] issued last iteration.
#define GATHER_TILE(UVPTR)                                                      \
    int lane = threadIdx.x & 63;                                                \
    int wave = threadIdx.x >> 6;                                                \
    int j4 = lane & 3, g = lane >> 2;                                           \
    int nodeBase = blockIdx.x * NPBLK + wave * NPW;                             \
    int r0c = 0, r1c = 0;                                                       \
    unsigned svc[PFD]; uint2 uvc[PFD];                                          \
    {   int node = nodeBase;                                                    \
        if (node < N) { r0c = rowptr[node]; r1c = rowptr[node + 1]; }           \
        _Pragma("unroll")                                                       \
        for (int m = 0; m < PFD; m++) {                                         \
            int k = r0c + g + 16 * m;                                           \
            if (k < r1c) svc[m] = sorted[k];                                    \
        }                                                                       \
        _Pragma("unroll")                                                       \
        for (int m = 0; m < PFD; m++) {                                         \
            int k = r0c + g + 16 * m;                                           \
            if (k < r1c) uvc[m] = UVPTR[(size_t)(svc[m] & 0x1FFFF) * 4 + j4];   \
        }                                                                       \
    }                                                                           \
    for (int t = 0; t < NPW; t++) {                                             \
        int r0n = 0, r1n = 0;                                                   \
        unsigned svn[PFD];                                                      \
        if (t < NPW - 1) {                                                      \
            int nn = nodeBase + t + 1;                                          \
            if (nn < N) { r0n = rowptr[nn]; r1n = rowptr[nn + 1]; }             \
            _Pragma("unroll")                                                   \
            for (int m = 0; m < PFD; m++) {                                     \
                int k = r0n + g + 16 * m;                                       \
                if (k < r1n) svn[m] = sorted[k];                                \
            }                                                                   \
        }                                                                       \
        float ax = 0.f, ay = 0.f, az = 0.f, aw = 0.f;                           \
        _Pragma("unroll")                                                       \
        for (int m = 0; m < PFD; m++) {                                         \
            int k = r0c + g + 16 * m;                                           \
            if (k < r1c) {                                                      \
                ax += bflo(uvc[m].x); ay += bfhi(uvc[m].x);                     \
                az += bflo(uvc[m].y); aw += bfhi(uvc[m].y);                     \
            }                                                                   \
        }                                                                       \
        for (int k = r0c + g + 16 * PFD; k < r1c; k += 16) {                    \
            uint2 va = UVPTR[(size_t)(sorted[k] & 0x1FFFF) * 4 + j4];           \
            ax += bflo(va.x); ay += bfhi(va.x);                                 \
            az += bflo(va.y); aw += bfhi(va.y);                                 \
        }                                                                       \
        ax += __shfl_xor(ax, 4);  ay += __shfl_xor(ay, 4);                      \
        az += __shfl_xor(az, 4);  aw += __shfl_xor(aw, 4);                      \
        ax += __shfl_xor(ax, 8);  ay += __shfl_xor(ay, 8);                      \
        az += __shfl_xor(az, 8);  aw += __shfl_xor(aw, 8);                      \
        ax += __shfl_xor(ax, 16); ay += __shfl_xor(ay, 16);                     \
        az += __shfl_xor(az, 16); aw += __shfl_xor(aw, 16);                     \
        ax += __shfl_xor(ax, 32); ay += __shfl_xor(ay, 32);                     \
        az += __shfl_xor(az, 32); aw += __shfl_xor(aw, 32);                     \
        if (g == 0) {                                                           \
            float* tp = &tile[(wave * NPW + t) * 16 + 4 * j4];                  \
            tp[0] = ax; tp[1] = ay; tp[2] = az; tp[3] = aw;                     \
        }                                                                       \
        if (t < NPW - 1) {                                                      \
            r0c = r0n; r1c = r1n;                                               \
            _Pragma("unroll")                                                   \
            for (int m = 0; m < PFD; m++) {                                     \
                int k = r0n + g + 16 * m;                                       \
                svc[m] = svn[m];                                                \
                if (k < r1n) uvc[m] = UVPTR[(size_t)(svn[m] & 0x1FFFF) * 4 + j4]; \
            }                                                                   \
        }                                                                       \
    }

// ---- layer-1 gather + finalize ----
__global__ void gatherfin1_kernel(const unsigned* __restrict__ sorted, const int* __restrict__ rowptr,
                                  const bf16* __restrict__ u, const float* __restrict__ dinv,
                                  const float* __restrict__ b1, const float* __restrict__ W2,
                                  bf16* __restrict__ u2, int N) {
    __shared__ float tile[NPBLK * 16];
    __shared__ float sW2[256];
    __shared__ float sb1[16];
    sW2[threadIdx.x] = W2[threadIdx.x];
    if (threadIdx.x < 16) sb1[threadIdx.x] = b1[threadIdx.x];

    const uint2* uvp = (const uint2*)u;   // [node*4 + j4] channel quads
    GATHER_TILE(uvp)
    __syncthreads();

    int jj = threadIdx.x & 15;
    for (int rr = 0; rr < NPBLK / 16; rr++) {
        int rl = (threadIdx.x >> 4) + rr * 16;
        int node = blockIdx.x * NPBLK + rl;
        float h = 0.f, di = 0.f;
        if (node < N) {
            di = dinv[node];
            h = di * (tile[rl * 16 + jj] + __bfloat162float(u[(size_t)node * H + jj])) + sb1[jj];
            h = fmaxf(h, 0.f);
        }
        float acc2 = 0.f;
#pragma unroll
        for (int kk = 0; kk < 16; kk++) {
            float hk = __shfl(h, kk, 16);
            acc2 += hk * sW2[kk * 16 + jj];
        }
        if (node < N) u2[(size_t)node * H + jj] = __float2bfloat16(di * acc2);
    }
}

// ---- layer-2 gather + finalize: log_softmax -> out (f32) ----
__global__ void gatherfin2_kernel(const unsigned* __restrict__ sorted, const int* __restrict__ rowptr,
                                  const bf16* __restrict__ u2, const float* __restrict__ dinv,
                                  const float* __restrict__ b2, float* __restrict__ out, int N) {
    __shared__ float tile[NPBLK * 16];
    __shared__ float sb2[16];
    if (threadIdx.x < 16) sb2[threadIdx.x] = b2[threadIdx.x];

    const uint2* uvp = (const uint2*)u2;
    GATHER_TILE(uvp)
    __syncthreads();

    int jj = threadIdx.x & 15;
    for (int rr = 0; rr < NPBLK / 16; rr++) {
        int rl = (threadIdx.x >> 4) + rr * 16;
        int node = blockIdx.x * NPBLK + rl;
        if (node >= N) continue;
        float di = dinv[node];
        float v = di * (tile[rl * 16 + jj] + __bfloat162float(u2[(size_t)node * H + jj])) + sb2[jj];

        float m = v;
#pragma unroll
        for (int off = 8; off >= 1; off >>= 1) m = fmaxf(m, __shfl_xor(m, off, 16));
        float ex = __expf(v - m);
        float s = ex;
#pragma unroll
        for (int off = 8; off >= 1; off >>= 1) s += __shfl_xor(s, off, 16);

        out[(size_t)node * H + jj] = v - m - __logf(s);
    }
}

extern "C" void kernel_launch(void* const* d_in, const int* in_sizes, int n_in,
                              void* d_out, int out_size, void* d_ws, size_t ws_size,
                              hipStream_t stream) {
    const float* x = (const float*)d_in[0];
    const int* edge_index = (const int*)d_in[1];
    const float* W1 = (const float*)d_in[2];
    const float* b1 = (const float*)d_in[3];
    const float* W2 = (const float*)d_in[4];
    const float* b2 = (const float*)d_in[5];
    float* out = (float*)d_out;

    const int N = in_sizes[0] / F_IN;        // 100000
    const int E = in_sizes[1] / 2;           // 3200000
    const int* src = edge_index;
    const int* dst = edge_index + E;
    const int NB = (N + NPB - 1) / NPB;      // 782

    // ws (4B units): dinv[N] | u[8N] | u2[8N] | packed[E] | sorted[E] |
    //                hist_t[MAX_NB*NBLK] | rowptr[N+1] | btot[NB] | base[NB+1]
    float* dinv = (float*)d_ws;
    bf16* u = (bf16*)(dinv + N);
    bf16* u2 = (bf16*)((unsigned*)u + (size_t)N * H / 2);
    unsigned* packed = (unsigned*)((unsigned*)u2 + (size_t)N * H / 2);
    unsigned* sorted = packed + E;
    int* hist_t = (int*)(sorted + E);
    int* rowptr = hist_t + (size_t)MAX_NB * NBLK;
    int* btot = rowptr + N + 1;
    int* base = btot + NB;

    histA_kernel<<<NBLK, BINT, 0, stream>>>(dst, hist_t, E, NB);
    colscan_kernel<<<NB, NBLK, 0, stream>>>(hist_t, btot);
    bucketscan_kernel<<<1, 1024, 0, stream>>>(btot, base, NB);
    binC_kernel<<<NBLK, BINT, 0, stream>>>(src, dst, hist_t, base, packed, E, NB);
    sortcsr_kernel<<<NB, 512, 0, stream>>>(packed, base, sorted, rowptr, dinv, N, E);

    xw1_kernel<<<(N + 15) / 16, 256, 0, stream>>>(x, W1, dinv, u, N);
    gatherfin1_kernel<<<(N + NPBLK - 1) / NPBLK, 256, 0, stream>>>(sorted, rowptr, u, dinv, b1, W2, u2, N);
    gatherfin2_kernel<<<(N + NPBLK - 1) / NPBLK, 256, 0, stream>>>(sorted, rowptr, u2, dinv, b2, out, N);
}

// Round 4
// 224.300 us; speedup vs baseline: 1.1091x; 1.0296x over previous
//
#include <hip/hip_runtime.h>
#include <hip/hip_bf16.h>
#include <math.h>

// N = 100000, E = 3.2M, F_in = 128, H = C = 16. int inputs arrive as int32.
//
// out[d] = dinv[d]*(sum_{s->d} u[s] + u[d]) + b,  u = dinv .* (h @ W).
// R3: global f32 atomics ~19.5G txn/s. R5: LDS f32 atomics ~3cy/lane.
// R6: sort->CSR->register gather. R7: bf16 messages. R8: 2-pass radix bin.
// R9: XCD swizzle. R10: pipelined gathers = 242us. R11/R12 REGRESSED.
// R13: R10 + uint2 gather lanes (4 ch/lane, 16 slots) = 234us.
// R14 REGRESSED (248.8us): deeper pipeline + shfl rowptr broadcast.
// R15 NEUTRAL-NEG (239.7us): clamped unconditional prefetch.
// R16 WIN (230.9us): 8 nodes/wave -> 12.5K waves (~49/CU oversubscribed).
//      Gathers ~38us each, still latency/issue-bound (VALUBusy ~27%).
// R17: 2 lanes per edge via uint4 (8 bf16 ch, 16B/lane), TWO nodes per
//      wave-iteration (lane = j8 x p x g[16 slots]). Halves gather VMEM
//      instructions per node (6 -> 3) at identical accumulate/shuffle cost
//      per node. Pipeline/PFD/NPW/grid unchanged from R16.

#define F_IN 128
#define H 16
#define NPB 128            // nodes per bucket
#define MAX_NB 800         // max buckets (N <= 102400)
#define NBLK 256           // binning blocks (must match hist partition)
#define BINT 1024          // binning threads per block
#define SMAX 4864          // max edges per bucket (mean 4096, +12 sigma)
#define PFD 3              // prefetch depth: 16 slots * 3 = 48 edges/node
#define NPW 8              // nodes per wave
#define NPBLK 32           // nodes per block = 4 waves * NPW

typedef __hip_bfloat16 bf16;

__device__ __forceinline__ float bflo(unsigned v) { return __uint_as_float(v << 16); }
__device__ __forceinline__ float bfhi(unsigned v) { return __uint_as_float(v & 0xffff0000u); }

// physical block -> logical block so logically-adjacent blocks (adjacent output
// runs in packed[]) land on the same XCD (XCD = physical % 8 round-robin).
__device__ __forceinline__ int swz(int p) { return (p & 7) * 32 + (p >> 3); }

// ---- pass A: per-block bucket histogram -> hist_t[bucket*NBLK + block] ----
__global__ void histA_kernel(const int* __restrict__ dst, int* __restrict__ hist_t,
                             int E, int NB) {
    __shared__ int h[MAX_NB];
    int b = swz(blockIdx.x);
    long long e0 = (long long)E * b / NBLK;
    long long e1 = (long long)E * (b + 1) / NBLK;
    for (int i = threadIdx.x; i < NB; i += BINT) h[i] = 0;
    __syncthreads();
    for (long long e = e0 + threadIdx.x; e < e1; e += BINT)
        atomicAdd(&h[dst[e] >> 7], 1);
    __syncthreads();
    for (int i = threadIdx.x; i < NB; i += BINT) hist_t[i * NBLK + b] = h[i];
}

// ---- pass B1: per-bucket exclusive scan over blocks + bucket totals ----
__global__ void colscan_kernel(int* __restrict__ hist_t, int* __restrict__ btot) {
    __shared__ int s[NBLK];
    int j = blockIdx.x;
    int t = threadIdx.x;
    int v = hist_t[j * NBLK + t];
    s[t] = v;
    __syncthreads();
    for (int off = 1; off < NBLK; off <<= 1) {
        int w = (t >= off) ? s[t - off] : 0;
        __syncthreads();
        s[t] += w;
        __syncthreads();
    }
    hist_t[j * NBLK + t] = s[t] - v;
    if (t == NBLK - 1) btot[j] = s[t];
}

// ---- pass B2: exclusive scan over bucket totals -> base[] ----
__global__ void bucketscan_kernel(const int* __restrict__ btot, int* __restrict__ base, int NB) {
    __shared__ int s[1024];
    int t = threadIdx.x;
    s[t] = (t < NB) ? btot[t] : 0;
    __syncthreads();
    for (int off = 1; off < 1024; off <<= 1) {
        int v = (t >= off) ? s[t - off] : 0;
        __syncthreads();
        s[t] += v;
        __syncthreads();
    }
    if (t < NB) base[t] = s[t] - btot[t];
    if (t == NB - 1) base[NB] = s[t];
}

// ---- pass C: place edges; packed = (dst&127)<<17 | src; LDS cursors only ----
__global__ void binC_kernel(const int* __restrict__ src, const int* __restrict__ dst,
                            const int* __restrict__ hist_t, const int* __restrict__ base,
                            unsigned* __restrict__ packed, int E, int NB) {
    __shared__ int pos[MAX_NB];
    int b = swz(blockIdx.x);
    long long e0 = (long long)E * b / NBLK;
    long long e1 = (long long)E * (b + 1) / NBLK;
    for (int i = threadIdx.x; i < NB; i += BINT)
        pos[i] = base[i] + hist_t[i * NBLK + b];
    __syncthreads();
    for (long long e = e0 + threadIdx.x; e < e1; e += BINT) {
        int d = dst[e];
        int bk = d >> 7;
        int p = atomicAdd(&pos[bk], 1);
        packed[p] = (unsigned)src[e] | ((unsigned)(d & 127) << 17);
    }
}

// ---- pass D: per-bucket LDS counting sort -> sorted[], rowptr[], dinv[] ----
__global__ void sortcsr_kernel(const unsigned* __restrict__ packed, const int* __restrict__ base,
                               unsigned* __restrict__ sorted, int* __restrict__ rowptr,
                               float* __restrict__ dinv, int N, int E) {
    __shared__ unsigned ssort[SMAX];
    __shared__ int cnt[NPB], offs[NPB], cur[NPB];
    int b = blockIdx.x;
    int e0 = base[b];
    int len = base[b + 1] - e0;
    if (len > SMAX) len = SMAX;
    int T = blockDim.x;

    for (int i = threadIdx.x; i < NPB; i += T) cnt[i] = 0;
    __syncthreads();
    for (int i = threadIdx.x; i < len; i += T)
        atomicAdd(&cnt[packed[e0 + i] >> 17], 1);
    __syncthreads();
    if (threadIdx.x < NPB) offs[threadIdx.x] = cnt[threadIdx.x];
    __syncthreads();
    for (int off = 1; off < NPB; off <<= 1) {
        int v = 0;
        if (threadIdx.x < NPB && threadIdx.x >= off) v = offs[threadIdx.x - off];
        __syncthreads();
        if (threadIdx.x < NPB) offs[threadIdx.x] += v;
        __syncthreads();
    }
    if (threadIdx.x < NPB) {
        int ex = offs[threadIdx.x] - cnt[threadIdx.x];
        cur[threadIdx.x] = ex;
        int node = b * NPB + threadIdx.x;
        if (node < N) {
            rowptr[node] = e0 + ex;
            dinv[node] = rsqrtf(1.0f + (float)cnt[threadIdx.x]);
        }
    }
    __syncthreads();
    for (int i = threadIdx.x; i < len; i += T) {
        unsigned p = packed[e0 + i];
        int pos = atomicAdd(&cur[p >> 17], 1);
        ssort[pos] = p;
    }
    __syncthreads();
    for (int i = threadIdx.x; i < len; i += T) sorted[e0 + i] = ssort[i];
    if (b == 0 && threadIdx.x == 0) rowptr[N] = E;
}

// ---- u[i][j] = dinv[i] * sum_k x[i][k]*W1[k][j]  (bf16 out) ----
#define XPAD 132
__global__ void xw1_kernel(const float* __restrict__ x, const float* __restrict__ W1,
                           const float* __restrict__ dinv, bf16* __restrict__ u, int n) {
    __shared__ float sW1[F_IN * H];
    __shared__ float sx[16 * XPAD];
    for (int t = threadIdx.x; t < F_IN * H; t += blockDim.x) sW1[t] = W1[t];

    int basei = blockIdx.x * 16;
    for (int idx = threadIdx.x; idx < 512; idx += 256) {
        int r = idx >> 5;
        int kk = (idx & 31) << 2;
        int row = basei + r;
        float4 v = make_float4(0.f, 0.f, 0.f, 0.f);
        if (row < n) v = *(const float4*)(x + (size_t)row * F_IN + kk);
        *(float4*)(sx + r * XPAD + kk) = v;
    }
    __syncthreads();

    int r = threadIdx.x >> 4;
    int j = threadIdx.x & 15;
    int row = basei + r;
    if (row >= n) return;

    const float* xr = sx + r * XPAD;
    float acc = 0.0f;
#pragma unroll 16
    for (int k = 0; k < F_IN; k++) acc += xr[k] * sW1[k * H + j];
    u[(size_t)row * H + j] = __float2bfloat16(dinv[row] * acc);
}

// ================= pipelined gather core (shared by both layers) =============
// R17 lane layout: b0 = j8 (channel octet: 8 bf16 = uint4 = 16B),
// b1 = p (node parity: 2 nodes per wave-iteration), b2..b5 = g (slot 0..15).
// Per node-pair iteration: each lane accumulates uint4 payloads for its
// (p, g) slots; reduce over g = __shfl_xor 4,8,16,32 (both nodes in
// parallel); lanes g==0 (0..3) write 8 channels each to the LDS tile.
// Depth-2 pipeline (R13 shape): prefetch sorted for pair t+1 while consuming
// uv for pair t; uv for t+1 issued after the consume.
#define GATHER_TILE(UVPTR)                                                      \
    int lane = threadIdx.x & 63;                                                \
    int wave = threadIdx.x >> 6;                                                \
    int j8 = lane & 1, pp = (lane >> 1) & 1, g = lane >> 2;                     \
    int nodeBase = blockIdx.x * NPBLK + wave * NPW;                             \
    int r0c = 0, r1c = 0;                                                       \
    unsigned svc[PFD]; uint4 uvc[PFD];                                          \
    {   int node = nodeBase + pp;                                               \
        if (node < N) { r0c = rowptr[node]; r1c = rowptr[node + 1]; }           \
        _Pragma("unroll")                                                       \
        for (int m = 0; m < PFD; m++) {                                         \
            int k = r0c + g + 16 * m;                                           \
            if (k < r1c) svc[m] = sorted[k];                                    \
        }                                                                       \
        _Pragma("unroll")                                                       \
        for (int m = 0; m < PFD; m++) {                                         \
            int k = r0c + g + 16 * m;                                           \
            if (k < r1c) uvc[m] = UVPTR[(size_t)(svc[m] & 0x1FFFF) * 2 + j8];   \
        }                                                                       \
    }                                                                           \
    for (int t = 0; t < NPW / 2; t++) {                                         \
        int r0n = 0, r1n = 0;                                                   \
        unsigned svn[PFD];                                                      \
        if (t < NPW / 2 - 1) {                                                  \
            int nn = nodeBase + 2 * (t + 1) + pp;                               \
            if (nn < N) { r0n = rowptr[nn]; r1n = rowptr[nn + 1]; }             \
            _Pragma("unroll")                                                   \
            for (int m = 0; m < PFD; m++) {                                     \
                int k = r0n + g + 16 * m;                                       \
                if (k < r1n) svn[m] = sorted[k];                                \
            }                                                                   \
        }                                                                       \
        float a0=0.f,a1=0.f,a2=0.f,a3=0.f,a4=0.f,a5=0.f,a6=0.f,a7=0.f;          \
        _Pragma("unroll")                                                       \
        for (int m = 0; m < PFD; m++) {                                         \
            int k = r0c + g + 16 * m;                                           \
            if (k < r1c) {                                                      \
                a0 += bflo(uvc[m].x); a1 += bfhi(uvc[m].x);                     \
                a2 += bflo(uvc[m].y); a3 += bfhi(uvc[m].y);                     \
                a4 += bflo(uvc[m].z); a5 += bfhi(uvc[m].z);                     \
                a6 += bflo(uvc[m].w); a7 += bfhi(uvc[m].w);                     \
            }                                                                   \
        }                                                                       \
        for (int k = r0c + g + 16 * PFD; k < r1c; k += 16) {                    \
            uint4 va = UVPTR[(size_t)(sorted[k] & 0x1FFFF) * 2 + j8];           \
            a0 += bflo(va.x); a1 += bfhi(va.x);                                 \
            a2 += bflo(va.y); a3 += bfhi(va.y);                                 \
            a4 += bflo(va.z); a5 += bfhi(va.z);                                 \
            a6 += bflo(va.w); a7 += bfhi(va.w);                                 \
        }                                                                       \
        _Pragma("unroll")                                                       \
        for (int off = 4; off <= 32; off <<= 1) {                               \
            a0 += __shfl_xor(a0, off); a1 += __shfl_xor(a1, off);               \
            a2 += __shfl_xor(a2, off); a3 += __shfl_xor(a3, off);               \
            a4 += __shfl_xor(a4, off); a5 += __shfl_xor(a5, off);               \
            a6 += __shfl_xor(a6, off); a7 += __shfl_xor(a7, off);               \
        }                                                                       \
        if (g == 0) {                                                           \
            float* tp = &tile[(wave * NPW + 2 * t + pp) * 16 + 8 * j8];         \
            tp[0]=a0; tp[1]=a1; tp[2]=a2; tp[3]=a3;                             \
            tp[4]=a4; tp[5]=a5; tp[6]=a6; tp[7]=a7;                             \
        }                                                                       \
        if (t < NPW / 2 - 1) {                                                  \
            r0c = r0n; r1c = r1n;                                               \
            _Pragma("unroll")                                                   \
            for (int m = 0; m < PFD; m++) {                                     \
                int k = r0n + g + 16 * m;                                       \
                svc[m] = svn[m];                                                \
                if (k < r1n) uvc[m] = UVPTR[(size_t)(svn[m] & 0x1FFFF) * 2 + j8]; \
            }                                                                   \
        }                                                                       \
    }

// ---- layer-1 gather + finalize ----
__global__ void gatherfin1_kernel(const unsigned* __restrict__ sorted, const int* __restrict__ rowptr,
                                  const bf16* __restrict__ u, const float* __restrict__ dinv,
                                  const float* __restrict__ b1, const float* __restrict__ W2,
                                  bf16* __restrict__ u2, int N) {
    __shared__ float tile[NPBLK * 16];
    __shared__ float sW2[256];
    __shared__ float sb1[16];
    sW2[threadIdx.x] = W2[threadIdx.x];
    if (threadIdx.x < 16) sb1[threadIdx.x] = b1[threadIdx.x];

    const uint4* uvp = (const uint4*)u;   // [node*2 + j8] channel octets
    GATHER_TILE(uvp)
    __syncthreads();

    int jj = threadIdx.x & 15;
    for (int rr = 0; rr < NPBLK / 16; rr++) {
        int rl = (threadIdx.x >> 4) + rr * 16;
        int node = blockIdx.x * NPBLK + rl;
        float h = 0.f, di = 0.f;
        if (node < N) {
            di = dinv[node];
            h = di * (tile[rl * 16 + jj] + __bfloat162float(u[(size_t)node * H + jj])) + sb1[jj];
            h = fmaxf(h, 0.f);
        }
        float acc2 = 0.f;
#pragma unroll
        for (int kk = 0; kk < 16; kk++) {
            float hk = __shfl(h, kk, 16);
            acc2 += hk * sW2[kk * 16 + jj];
        }
        if (node < N) u2[(size_t)node * H + jj] = __float2bfloat16(di * acc2);
    }
}

// ---- layer-2 gather + finalize: log_softmax -> out (f32) ----
__global__ void gatherfin2_kernel(const unsigned* __restrict__ sorted, const int* __restrict__ rowptr,
                                  const bf16* __restrict__ u2, const float* __restrict__ dinv,
                                  const float* __restrict__ b2, float* __restrict__ out, int N) {
    __shared__ float tile[NPBLK * 16];
    __shared__ float sb2[16];
    if (threadIdx.x < 16) sb2[threadIdx.x] = b2[threadIdx.x];

    const uint4* uvp = (const uint4*)u2;
    GATHER_TILE(uvp)
    __syncthreads();

    int jj = threadIdx.x & 15;
    for (int rr = 0; rr < NPBLK / 16; rr++) {
        int rl = (threadIdx.x >> 4) + rr * 16;
        int node = blockIdx.x * NPBLK + rl;
        if (node >= N) continue;
        float di = dinv[node];
        float v = di * (tile[rl * 16 + jj] + __bfloat162float(u2[(size_t)node * H + jj])) + sb2[jj];

        float m = v;
#pragma unroll
        for (int off = 8; off >= 1; off >>= 1) m = fmaxf(m, __shfl_xor(m, off, 16));
        float ex = __expf(v - m);
        float s = ex;
#pragma unroll
        for (int off = 8; off >= 1; off >>= 1) s += __shfl_xor(s, off, 16);

        out[(size_t)node * H + jj] = v - m - __logf(s);
    }
}

extern "C" void kernel_launch(void* const* d_in, const int* in_sizes, int n_in,
                              void* d_out, int out_size, void* d_ws, size_t ws_size,
                              hipStream_t stream) {
    const float* x = (const float*)d_in[0];
    const int* edge_index = (const int*)d_in[1];
    const float* W1 = (const float*)d_in[2];
    const float* b1 = (const float*)d_in[3];
    const float* W2 = (const float*)d_in[4];
    const float* b2 = (const float*)d_in[5];
    float* out = (float*)d_out;

    const int N = in_sizes[0] / F_IN;        // 100000
    const int E = in_sizes[1] / 2;           // 3200000
    const int* src = edge_index;
    const int* dst = edge_index + E;
    const int NB = (N + NPB - 1) / NPB;      // 782

    // ws (4B units): dinv[N] | u[8N] | u2[8N] | packed[E] | sorted[E] |
    //                hist_t[MAX_NB*NBLK] | rowptr[N+1] | btot[NB] | base[NB+1]
    float* dinv = (float*)d_ws;
    bf16* u = (bf16*)(dinv + N);
    bf16* u2 = (bf16*)((unsigned*)u + (size_t)N * H / 2);
    unsigned* packed = (unsigned*)((unsigned*)u2 + (size_t)N * H / 2);
    unsigned* sorted = packed + E;
    int* hist_t = (int*)(sorted + E);
    int* rowptr = hist_t + (size_t)MAX_NB * NBLK;
    int* btot = rowptr + N + 1;
    int* base = btot + NB;

    histA_kernel<<<NBLK, BINT, 0, stream>>>(dst, hist_t, E, NB);
    colscan_kernel<<<NB, NBLK, 0, stream>>>(hist_t, btot);
    bucketscan_kernel<<<1, 1024, 0, stream>>>(btot, base, NB);
    binC_kernel<<<NBLK, BINT, 0, stream>>>(src, dst, hist_t, base, packed, E, NB);
    sortcsr_kernel<<<NB, 512, 0, stream>>>(packed, base, sorted, rowptr, dinv, N, E);

    xw1_kernel<<<(N + 15) / 16, 256, 0, stream>>>(x, W1, dinv, u, N);
    gatherfin1_kernel<<<(N + NPBLK - 1) / NPBLK, 256, 0, stream>>>(sorted, rowptr, u, dinv, b1, W2, u2, N);
    gatherfin2_kernel<<<(N + NPBLK - 1) / NPBLK, 256, 0, stream>>>(sorted, rowptr, u2, dinv, b2, out, N);
}

// Round 5
// 221.757 us; speedup vs baseline: 1.1218x; 1.0115x over previous
//
#include <hip/hip_runtime.h>
#include <hip/hip_bf16.h>
#include <math.h>

// N = 100000, E = 3.2M, F_in = 128, H = C = 16. int inputs arrive as int32.
//
// out[d] = dinv[d]*(sum_{s->d} u[s] + u[d]) + b,  u = dinv .* (h @ W).
// R3: global f32 atomics ~19.5G txn/s (3.2M atomics = 164us -> unusable).
// R6: sort->CSR->register gather. R7: bf16 messages. R8: 2-pass radix bin.
// R9: XCD swizzle. R10: pipelined gathers = 242us. R11/R12 REGRESSED.
// R13: uint2 gather lanes = 234us. R14 REGRESSED (deep pipeline).
// R15 NEUTRAL-NEG (clamped prefetch).
// R16 WIN (230.9us): 8 nodes/wave -> ~49 waves/CU oversubscribed.
// R17 WIN (224.3us): uint4 gather lanes, 2 lanes/edge, 2 nodes/wave-iter.
//      Gathers now ~35us each. Preproc+xw1 ~153us is the fat now.
// R18: xw1 rewrite - 4 outputs/thread (lane = row x jq). LDS instrs per
//      output 256 -> 64 (1 b32 broadcast + 1 b128 float4 per k instead of
//      2 scalar b32 per k per output). Block covers 64 rows. Everything
//      else untouched.

#define F_IN 128
#define H 16
#define NPB 128            // nodes per bucket
#define MAX_NB 800         // max buckets (N <= 102400)
#define NBLK 256           // binning blocks (must match hist partition)
#define BINT 1024          // binning threads per block
#define SMAX 4864          // max edges per bucket (mean 4096, +12 sigma)
#define PFD 3              // prefetch depth: 16 slots * 3 = 48 edges/node
#define NPW 8              // nodes per wave
#define NPBLK 32           // nodes per block = 4 waves * NPW

typedef __hip_bfloat16 bf16;

__device__ __forceinline__ float bflo(unsigned v) { return __uint_as_float(v << 16); }
__device__ __forceinline__ float bfhi(unsigned v) { return __uint_as_float(v & 0xffff0000u); }

// physical block -> logical block so logically-adjacent blocks (adjacent output
// runs in packed[]) land on the same XCD (XCD = physical % 8 round-robin).
__device__ __forceinline__ int swz(int p) { return (p & 7) * 32 + (p >> 3); }

// ---- pass A: per-block bucket histogram -> hist_t[bucket*NBLK + block] ----
__global__ void histA_kernel(const int* __restrict__ dst, int* __restrict__ hist_t,
                             int E, int NB) {
    __shared__ int h[MAX_NB];
    int b = swz(blockIdx.x);
    long long e0 = (long long)E * b / NBLK;
    long long e1 = (long long)E * (b + 1) / NBLK;
    for (int i = threadIdx.x; i < NB; i += BINT) h[i] = 0;
    __syncthreads();
    for (long long e = e0 + threadIdx.x; e < e1; e += BINT)
        atomicAdd(&h[dst[e] >> 7], 1);
    __syncthreads();
    for (int i = threadIdx.x; i < NB; i += BINT) hist_t[i * NBLK + b] = h[i];
}

// ---- pass B1: per-bucket exclusive scan over blocks + bucket totals ----
__global__ void colscan_kernel(int* __restrict__ hist_t, int* __restrict__ btot) {
    __shared__ int s[NBLK];
    int j = blockIdx.x;
    int t = threadIdx.x;
    int v = hist_t[j * NBLK + t];
    s[t] = v;
    __syncthreads();
    for (int off = 1; off < NBLK; off <<= 1) {
        int w = (t >= off) ? s[t - off] : 0;
        __syncthreads();
        s[t] += w;
        __syncthreads();
    }
    hist_t[j * NBLK + t] = s[t] - v;
    if (t == NBLK - 1) btot[j] = s[t];
}

// ---- pass B2: exclusive scan over bucket totals -> base[] ----
__global__ void bucketscan_kernel(const int* __restrict__ btot, int* __restrict__ base, int NB) {
    __shared__ int s[1024];
    int t = threadIdx.x;
    s[t] = (t < NB) ? btot[t] : 0;
    __syncthreads();
    for (int off = 1; off < 1024; off <<= 1) {
        int v = (t >= off) ? s[t - off] : 0;
        __syncthreads();
        s[t] += v;
        __syncthreads();
    }
    if (t < NB) base[t] = s[t] - btot[t];
    if (t == NB - 1) base[NB] = s[t];
}

// ---- pass C: place edges; packed = (dst&127)<<17 | src; LDS cursors only ----
__global__ void binC_kernel(const int* __restrict__ src, const int* __restrict__ dst,
                            const int* __restrict__ hist_t, const int* __restrict__ base,
                            unsigned* __restrict__ packed, int E, int NB) {
    __shared__ int pos[MAX_NB];
    int b = swz(blockIdx.x);
    long long e0 = (long long)E * b / NBLK;
    long long e1 = (long long)E * (b + 1) / NBLK;
    for (int i = threadIdx.x; i < NB; i += BINT)
        pos[i] = base[i] + hist_t[i * NBLK + b];
    __syncthreads();
    for (long long e = e0 + threadIdx.x; e < e1; e += BINT) {
        int d = dst[e];
        int bk = d >> 7;
        int p = atomicAdd(&pos[bk], 1);
        packed[p] = (unsigned)src[e] | ((unsigned)(d & 127) << 17);
    }
}

// ---- pass D: per-bucket LDS counting sort -> sorted[], rowptr[], dinv[] ----
__global__ void sortcsr_kernel(const unsigned* __restrict__ packed, const int* __restrict__ base,
                               unsigned* __restrict__ sorted, int* __restrict__ rowptr,
                               float* __restrict__ dinv, int N, int E) {
    __shared__ unsigned ssort[SMAX];
    __shared__ int cnt[NPB], offs[NPB], cur[NPB];
    int b = blockIdx.x;
    int e0 = base[b];
    int len = base[b + 1] - e0;
    if (len > SMAX) len = SMAX;
    int T = blockDim.x;

    for (int i = threadIdx.x; i < NPB; i += T) cnt[i] = 0;
    __syncthreads();
    for (int i = threadIdx.x; i < len; i += T)
        atomicAdd(&cnt[packed[e0 + i] >> 17], 1);
    __syncthreads();
    if (threadIdx.x < NPB) offs[threadIdx.x] = cnt[threadIdx.x];
    __syncthreads();
    for (int off = 1; off < NPB; off <<= 1) {
        int v = 0;
        if (threadIdx.x < NPB && threadIdx.x >= off) v = offs[threadIdx.x - off];
        __syncthreads();
        if (threadIdx.x < NPB) offs[threadIdx.x] += v;
        __syncthreads();
    }
    if (threadIdx.x < NPB) {
        int ex = offs[threadIdx.x] - cnt[threadIdx.x];
        cur[threadIdx.x] = ex;
        int node = b * NPB + threadIdx.x;
        if (node < N) {
            rowptr[node] = e0 + ex;
            dinv[node] = rsqrtf(1.0f + (float)cnt[threadIdx.x]);
        }
    }
    __syncthreads();
    for (int i = threadIdx.x; i < len; i += T) {
        unsigned p = packed[e0 + i];
        int pos = atomicAdd(&cur[p >> 17], 1);
        ssort[pos] = p;
    }
    __syncthreads();
    for (int i = threadIdx.x; i < len; i += T) sorted[e0 + i] = ssort[i];
    if (b == 0 && threadIdx.x == 0) rowptr[N] = E;
}

// ---- u[i][j] = dinv[i] * sum_k x[i][k]*W1[k][j]  (bf16 out) ----
// R18: 4 outputs per thread. lane = (row r: tid>>2) x (jq: tid&3 -> 4 ch).
// Per k: 1 b32 broadcast (x) + 1 b128 (W1 quad) + 4 FMA. Block = 64 rows.
#define XR 64
#define XPAD 132
__global__ void xw1_kernel(const float* __restrict__ x, const float* __restrict__ W1,
                           const float* __restrict__ dinv, bf16* __restrict__ u, int n) {
    __shared__ float sW1[F_IN * H];        // 8 KB, [k*16 + j]
    __shared__ float sx[XR * XPAD];        // 33.8 KB
    for (int t = threadIdx.x; t < F_IN * H; t += 256) sW1[t] = W1[t];

    int basei = blockIdx.x * XR;
    for (int idx = threadIdx.x; idx < XR * 32; idx += 256) {
        int r = idx >> 5;                  // 0..63
        int kk = (idx & 31) << 2;          // 0,4,...,124
        int row = basei + r;
        float4 v = make_float4(0.f, 0.f, 0.f, 0.f);
        if (row < n) v = *(const float4*)(x + (size_t)row * F_IN + kk);
        *(float4*)(sx + r * XPAD + kk) = v;
    }
    __syncthreads();

    int r = threadIdx.x >> 2;              // 0..63
    int jq = (threadIdx.x & 3) << 2;       // 0,4,8,12
    int row = basei + r;
    if (row >= n) return;

    const float* xr = sx + r * XPAD;
    float a0 = 0.f, a1 = 0.f, a2 = 0.f, a3 = 0.f;
#pragma unroll 16
    for (int k = 0; k < F_IN; k++) {
        float xk = xr[k];
        float4 w = *(const float4*)(sW1 + k * H + jq);
        a0 += xk * w.x; a1 += xk * w.y; a2 += xk * w.z; a3 += xk * w.w;
    }
    float di = dinv[row];
    bf16 b0 = __float2bfloat16(di * a0);
    bf16 b1 = __float2bfloat16(di * a1);
    bf16 b2 = __float2bfloat16(di * a2);
    bf16 b3 = __float2bfloat16(di * a3);
    ushort4 pk = make_ushort4(*(unsigned short*)&b0, *(unsigned short*)&b1,
                              *(unsigned short*)&b2, *(unsigned short*)&b3);
    *(ushort4*)((unsigned short*)u + (size_t)row * H + jq) = pk;
}

// ================= pipelined gather core (shared by both layers) =============
// R17 lane layout: b0 = j8 (channel octet: 8 bf16 = uint4 = 16B),
// b1 = p (node parity: 2 nodes per wave-iteration), b2..b5 = g (slot 0..15).
// Per node-pair iteration: each lane accumulates uint4 payloads for its
// (p, g) slots; reduce over g = __shfl_xor 4,8,16,32 (both nodes in
// parallel); lanes g==0 (0..3) write 8 channels each to the LDS tile.
// Depth-2 pipeline (R13 shape): prefetch sorted for pair t+1 while consuming
// uv for pair t; uv for t+1 issued after the consume.
#define GATHER_TILE(UVPTR)                                                      \
    int lane = threadIdx.x & 63;                                                \
    int wave = threadIdx.x >> 6;                                                \
    int j8 = lane & 1, pp = (lane >> 1) & 1, g = lane >> 2;                     \
    int nodeBase = blockIdx.x * NPBLK + wave * NPW;                             \
    int r0c = 0, r1c = 0;                                                       \
    unsigned svc[PFD]; uint4 uvc[PFD];                                          \
    {   int node = nodeBase + pp;                                               \
        if (node < N) { r0c = rowptr[node]; r1c = rowptr[node + 1]; }           \
        _Pragma("unroll")                                                       \
        for (int m = 0; m < PFD; m++) {                                         \
            int k = r0c + g + 16 * m;                                           \
            if (k < r1c) svc[m] = sorted[k];                                    \
        }                                                                       \
        _Pragma("unroll")                                                       \
        for (int m = 0; m < PFD; m++) {                                         \
            int k = r0c + g + 16 * m;                                           \
            if (k < r1c) uvc[m] = UVPTR[(size_t)(svc[m] & 0x1FFFF) * 2 + j8];   \
        }                                                                       \
    }                                                                           \
    for (int t = 0; t < NPW / 2; t++) {                                         \
        int r0n = 0, r1n = 0;                                                   \
        unsigned svn[PFD];                                                      \
        if (t < NPW / 2 - 1) {                                                  \
            int nn = nodeBase + 2 * (t + 1) + pp;                               \
            if (nn < N) { r0n = rowptr[nn]; r1n = rowptr[nn + 1]; }             \
            _Pragma("unroll")                                                   \
            for (int m = 0; m < PFD; m++) {                                     \
                int k = r0n + g + 16 * m;                                       \
                if (k < r1n) svn[m] = sorted[k];                                \
            }                                                                   \
        }                                                                       \
        float a0=0.f,a1=0.f,a2=0.f,a3=0.f,a4=0.f,a5=0.f,a6=0.f,a7=0.f;          \
        _Pragma("unroll")                                                       \
        for (int m = 0; m < PFD; m++) {                                         \
            int k = r0c + g + 16 * m;                                           \
            if (k < r1c) {                                                      \
                a0 += bflo(uvc[m].x); a1 += bfhi(uvc[m].x);                     \
                a2 += bflo(uvc[m].y); a3 += bfhi(uvc[m].y);                     \
                a4 += bflo(uvc[m].z); a5 += bfhi(uvc[m].z);                     \
                a6 += bflo(uvc[m].w); a7 += bfhi(uvc[m].w);                     \
            }                                                                   \
        }                                                                       \
        for (int k = r0c + g + 16 * PFD; k < r1c; k += 16) {                    \
            uint4 va = UVPTR[(size_t)(sorted[k] & 0x1FFFF) * 2 + j8];           \
            a0 += bflo(va.x); a1 += bfhi(va.x);                                 \
            a2 += bflo(va.y); a3 += bfhi(va.y);                                 \
            a4 += bflo(va.z); a5 += bfhi(va.z);                                 \
            a6 += bflo(va.w); a7 += bfhi(va.w);                                 \
        }                                                                       \
        _Pragma("unroll")                                                       \
        for (int off = 4; off <= 32; off <<= 1) {                               \
            a0 += __shfl_xor(a0, off); a1 += __shfl_xor(a1, off);               \
            a2 += __shfl_xor(a2, off); a3 += __shfl_xor(a3, off);               \
            a4 += __shfl_xor(a4, off); a5 += __shfl_xor(a5, off);               \
            a6 += __shfl_xor(a6, off); a7 += __shfl_xor(a7, off);               \
        }                                                                       \
        if (g == 0) {                                                           \
            float* tp = &tile[(wave * NPW + 2 * t + pp) * 16 + 8 * j8];         \
            tp[0]=a0; tp[1]=a1; tp[2]=a2; tp[3]=a3;                             \
            tp[4]=a4; tp[5]=a5; tp[6]=a6; tp[7]=a7;                             \
        }                                                                       \
        if (t < NPW / 2 - 1) {                                                  \
            r0c = r0n; r1c = r1n;                                               \
            _Pragma("unroll")                                                   \
            for (int m = 0; m < PFD; m++) {                                     \
                int k = r0n + g + 16 * m;                                       \
                svc[m] = svn[m];                                                \
                if (k < r1n) uvc[m] = UVPTR[(size_t)(svn[m] & 0x1FFFF) * 2 + j8]; \
            }                                                                   \
        }                                                                       \
    }

// ---- layer-1 gather + finalize ----
__global__ void gatherfin1_kernel(const unsigned* __restrict__ sorted, const int* __restrict__ rowptr,
                                  const bf16* __restrict__ u, const float* __restrict__ dinv,
                                  const float* __restrict__ b1, const float* __restrict__ W2,
                                  bf16* __restrict__ u2, int N) {
    __shared__ float tile[NPBLK * 16];
    __shared__ float sW2[256];
    __shared__ float sb1[16];
    sW2[threadIdx.x] = W2[threadIdx.x];
    if (threadIdx.x < 16) sb1[threadIdx.x] = b1[threadIdx.x];

    const uint4* uvp = (const uint4*)u;   // [node*2 + j8] channel octets
    GATHER_TILE(uvp)
    __syncthreads();

    int jj = threadIdx.x & 15;
    for (int rr = 0; rr < NPBLK / 16; rr++) {
        int rl = (threadIdx.x >> 4) + rr * 16;
        int node = blockIdx.x * NPBLK + rl;
        float h = 0.f, di = 0.f;
        if (node < N) {
            di = dinv[node];
            h = di * (tile[rl * 16 + jj] + __bfloat162float(u[(size_t)node * H + jj])) + sb1[jj];
            h = fmaxf(h, 0.f);
        }
        float acc2 = 0.f;
#pragma unroll
        for (int kk = 0; kk < 16; kk++) {
            float hk = __shfl(h, kk, 16);
            acc2 += hk * sW2[kk * 16 + jj];
        }
        if (node < N) u2[(size_t)node * H + jj] = __float2bfloat16(di * acc2);
    }
}

// ---- layer-2 gather + finalize: log_softmax -> out (f32) ----
__global__ void gatherfin2_kernel(const unsigned* __restrict__ sorted, const int* __restrict__ rowptr,
                                  const bf16* __restrict__ u2, const float* __restrict__ dinv,
                                  const float* __restrict__ b2, float* __restrict__ out, int N) {
    __shared__ float tile[NPBLK * 16];
    __shared__ float sb2[16];
    if (threadIdx.x < 16) sb2[threadIdx.x] = b2[threadIdx.x];

    const uint4* uvp = (const uint4*)u2;
    GATHER_TILE(uvp)
    __syncthreads();

    int jj = threadIdx.x & 15;
    for (int rr = 0; rr < NPBLK / 16; rr++) {
        int rl = (threadIdx.x >> 4) + rr * 16;
        int node = blockIdx.x * NPBLK + rl;
        if (node >= N) continue;
        float di = dinv[node];
        float v = di * (tile[rl * 16 + jj] + __bfloat162float(u2[(size_t)node * H + jj])) + sb2[jj];

        float m = v;
#pragma unroll
        for (int off = 8; off >= 1; off >>= 1) m = fmaxf(m, __shfl_xor(m, off, 16));
        float ex = __expf(v - m);
        float s = ex;
#pragma unroll
        for (int off = 8; off >= 1; off >>= 1) s += __shfl_xor(s, off, 16);

        out[(size_t)node * H + jj] = v - m - __logf(s);
    }
}

extern "C" void kernel_launch(void* const* d_in, const int* in_sizes, int n_in,
                              void* d_out, int out_size, void* d_ws, size_t ws_size,
                              hipStream_t stream) {
    const float* x = (const float*)d_in[0];
    const int* edge_index = (const int*)d_in[1];
    const float* W1 = (const float*)d_in[2];
    const float* b1 = (const float*)d_in[3];
    const float* W2 = (const float*)d_in[4];
    const float* b2 = (const float*)d_in[5];
    float* out = (float*)d_out;

    const int N = in_sizes[0] / F_IN;        // 100000
    const int E = in_sizes[1] / 2;           // 3200000
    const int* src = edge_index;
    const int* dst = edge_index + E;
    const int NB = (N + NPB - 1) / NPB;      // 782

    // ws (4B units): dinv[N] | u[8N] | u2[8N] | packed[E] | sorted[E] |
    //                hist_t[MAX_NB*NBLK] | rowptr[N+1] | btot[NB] | base[NB+1]
    float* dinv = (float*)d_ws;
    bf16* u = (bf16*)(dinv + N);
    bf16* u2 = (bf16*)((unsigned*)u + (size_t)N * H / 2);
    unsigned* packed = (unsigned*)((unsigned*)u2 + (size_t)N * H / 2);
    unsigned* sorted = packed + E;
    int* hist_t = (int*)(sorted + E);
    int* rowptr = hist_t + (size_t)MAX_NB * NBLK;
    int* btot = rowptr + N + 1;
    int* base = btot + NB;

    histA_kernel<<<NBLK, BINT, 0, stream>>>(dst, hist_t, E, NB);
    colscan_kernel<<<NB, NBLK, 0, stream>>>(hist_t, btot);
    bucketscan_kernel<<<1, 1024, 0, stream>>>(btot, base, NB);
    binC_kernel<<<NBLK, BINT, 0, stream>>>(src, dst, hist_t, base, packed, E, NB);
    sortcsr_kernel<<<NB, 512, 0, stream>>>(packed, base, sorted, rowptr, dinv, N, E);

    xw1_kernel<<<(N + XR - 1) / XR, 256, 0, stream>>>(x, W1, dinv, u, N);
    gatherfin1_kernel<<<(N + NPBLK - 1) / NPBLK, 256, 0, stream>>>(sorted, rowptr, u, dinv, b1, W2, u2, N);
    gatherfin2_kernel<<<(N + NPBLK - 1) / NPBLK, 256, 0, stream>>>(sorted, rowptr, u2, dinv, b2, out, N);
}